// Round 3
// baseline (1747.808 us; speedup 1.0000x reference)
//
#include <hip/hip_runtime.h>
#include <hip/hip_bf16.h>
#include <hip/hip_fp16.h>

#define Tn 1024
#define Bn 64
#define En 128
#define G4 512
#define NEGV -10000.0f

// ---------- bf16 helpers ----------
__device__ __forceinline__ float bf2f(unsigned short u) {
    unsigned int v = ((unsigned int)u) << 16;
    float f;
    __builtin_memcpy(&f, &v, 4);
    return f;
}
__device__ __forceinline__ unsigned short f2bf(float f) {
    unsigned int u;
    __builtin_memcpy(&u, &f, 4);
    u = (u + 0x7fffu + ((u >> 16) & 1u)) >> 16;
    return (unsigned short)u;
}

// DPP cross-lane add (pure VALU, no LDS pipe). CTRL: 0xB1=xor1(quad_perm[1,0,3,2]),
// 0x4E=xor2(quad_perm[2,3,0,1]), 0x141=row_half_mirror (pairs the two quads of an octet).
template <int CTRL>
__device__ __forceinline__ float dpp_add(float a) {
    int v;
    __builtin_memcpy(&v, &a, 4);
    int m = __builtin_amdgcn_update_dpp(0, v, CTRL, 0xf, 0xf, true);
    float b;
    __builtin_memcpy(&b, &m, 4);
    return a + b;
}

__device__ __forceinline__ float sigf(float x) { return 1.0f / (1.0f + __expf(-x)); }
__device__ __forceinline__ float tanhfast(float x) { return 1.0f - 2.0f / (1.0f + __expf(2.0f * x)); }

// =====================================================================
// K1: input projection. G[d][t][b][g] = embed[tok(b,t)] . w_ih[g] + b_ih[g] + b_hh[g]
// GEMM: M=65536 rows (r = t*64+b), N=512, K=128. Tile 128x128, 8x8/thread.
// =====================================================================
__global__ __launch_bounds__(256) void k_inproj(
    const int* __restrict__ sent, const float* __restrict__ embed,
    const float* __restrict__ w_ih_f, const float* __restrict__ b_ih_f, const float* __restrict__ b_hh_f,
    const float* __restrict__ w_ih_b, const float* __restrict__ b_ih_b, const float* __restrict__ b_hh_b,
    unsigned short* __restrict__ G_f, unsigned short* __restrict__ G_b)
{
    __shared__ float Ald[64][128];   // [k'][row]
    __shared__ float Bld[64][128];   // [k'][gate]
    const int tid = threadIdx.x;
    const int dir = blockIdx.z;
    const float* w_ih = dir ? w_ih_b : w_ih_f;
    const float* bi   = dir ? b_ih_b : b_ih_f;
    const float* bh   = dir ? b_hh_b : b_hh_f;
    unsigned short* Gout = dir ? G_b : G_f;

    const int mt = blockIdx.x, nt = blockIdx.y;
    const int r0 = mt * 128, n0 = nt * 128;
    const int tx = tid & 15, ty = tid >> 4;

    // staging assignment: 2 threads per row, 32 k-values each
    const int sr = tid >> 1;
    const int kh = (tid & 1) * 32;
    const int rg = r0 + sr;
    const int tt = rg >> 6, bb = rg & 63;
    const int tok = sent[bb * Tn + tt];
    const float* arow = embed + (size_t)tok * En;
    const float* brow = w_ih + (size_t)(n0 + sr) * En;

    float acc[8][8];
#pragma unroll
    for (int i = 0; i < 8; ++i)
#pragma unroll
        for (int j = 0; j < 8; ++j) acc[i][j] = 0.0f;

    for (int kc = 0; kc < 2; ++kc) {
        const int kb = kc * 64 + kh;
#pragma unroll
        for (int s = 0; s < 32; s += 4) {
            float4 av = *(const float4*)(arow + kb + s);
            Ald[kh + s + 0][sr] = av.x; Ald[kh + s + 1][sr] = av.y;
            Ald[kh + s + 2][sr] = av.z; Ald[kh + s + 3][sr] = av.w;
            float4 bv = *(const float4*)(brow + kb + s);
            Bld[kh + s + 0][sr] = bv.x; Bld[kh + s + 1][sr] = bv.y;
            Bld[kh + s + 2][sr] = bv.z; Bld[kh + s + 3][sr] = bv.w;
        }
        __syncthreads();
#pragma unroll 4
        for (int k = 0; k < 64; ++k) {
            float a[8], bv[8];
            *(float4*)&a[0]  = *(const float4*)&Ald[k][ty * 8];
            *(float4*)&a[4]  = *(const float4*)&Ald[k][ty * 8 + 4];
            *(float4*)&bv[0] = *(const float4*)&Bld[k][tx * 8];
            *(float4*)&bv[4] = *(const float4*)&Bld[k][tx * 8 + 4];
#pragma unroll
            for (int i = 0; i < 8; ++i)
#pragma unroll
                for (int j = 0; j < 8; ++j) acc[i][j] += a[i] * bv[j];
        }
        __syncthreads();
    }

    float bias[8];
#pragma unroll
    for (int j = 0; j < 8; ++j) {
        int g = n0 + tx * 8 + j;
        bias[j] = bi[g] + bh[g];
    }
#pragma unroll
    for (int i = 0; i < 8; ++i) {
        int r = r0 + ty * 8 + i;
        int t = r >> 6, b2 = r & 63;
        unsigned int p0 = (unsigned int)f2bf(acc[i][0] + bias[0]) | ((unsigned int)f2bf(acc[i][1] + bias[1]) << 16);
        unsigned int p1 = (unsigned int)f2bf(acc[i][2] + bias[2]) | ((unsigned int)f2bf(acc[i][3] + bias[3]) << 16);
        unsigned int p2 = (unsigned int)f2bf(acc[i][4] + bias[4]) | ((unsigned int)f2bf(acc[i][5] + bias[5]) << 16);
        unsigned int p3 = (unsigned int)f2bf(acc[i][6] + bias[6]) | ((unsigned int)f2bf(acc[i][7] + bias[7]) << 16);
        uint4 v; v.x = p0; v.y = p1; v.z = p2; v.w = p3;
        *((uint4*)(Gout + (((size_t)t * Bn + b2) << 9) + n0 + tx * 8)) = v;
    }
}

// =====================================================================
// K2: LSTM recurrence, split-k + DPP reduce.
// One workgroup per (batch, dir), 512 threads = 8 waves.
// Wave wv owns j in [wv*16, wv*16+16). Octet g (lanes g*8..g*8+7) owns the
// j-pair (j0=wv*16+2g, j1=j0+1) x 4 gates = 8 rows. Lane member o=lane&7
// covers k-slice [16o, 16o+16). Dots accumulate in packed f16 (__hfma2),
// reduced across the octet with 3 DPP stages (no LDS traffic).
// h kept in LDS as f16 (64 dwords), double-buffered; ONE barrier per step.
// =====================================================================
__global__ __launch_bounds__(512, 2) void k_lstm(
    const float* __restrict__ whh_f, const float* __restrict__ whh_b,
    const unsigned short* __restrict__ G_f, const unsigned short* __restrict__ G_b,
    unsigned short* __restrict__ h_f, unsigned short* __restrict__ h_b)
{
    const int tid = threadIdx.x;
    const int wv = tid >> 6;
    const int lane = tid & 63;
    const int g = lane >> 3;       // octet within wave
    const int o = lane & 7;        // k-slice member
    const int b = blockIdx.x;
    const int dir = blockIdx.y;
    const float* whh = dir ? whh_b : whh_f;
    const unsigned short* G = dir ? G_b : G_f;
    unsigned short* ho = dir ? h_b : h_f;

    const int j0 = wv * 16 + 2 * g;   // even
    const int jhalf = j0 >> 1;

    __shared__ __align__(16) unsigned hls[2][64];   // 2 x 128 f16

    // Load weights for the octet's 8 rows, k-slice [16o,16o+16), as f16 pairs.
    // Row i: gate q=i&3, j = j0 + (i>>2); original row index = q*128 + j.
    __half2 wpk[8][8];
#pragma unroll
    for (int i = 0; i < 8; ++i) {
        const int q = i & 3;
        const int jj = j0 + (i >> 2);
        const float2* wr = (const float2*)(whh + (size_t)(q * 128 + jj) * 128 + o * 16);
#pragma unroll
        for (int kk = 0; kk < 8; ++kk) {
            float2 wv2 = wr[kk];
            wpk[i][kk] = __floats2half2_rn(wv2.x, wv2.y);
        }
    }

    if (tid < 128) ((unsigned*)hls)[tid] = 0u;   // zero both h buffers
    float c0 = 0.0f, c1 = 0.0f;
    __syncthreads();

    int t = dir ? (Tn - 1) : 0;
    const int dt = dir ? -1 : 1;

    // G pre-activation loads: 4 dwords (bf16 pairs j0,j1) at rows q*128+j0.
    unsigned gd[4];
    {
        const unsigned* gp = (const unsigned*)(G + (((size_t)t * Bn + b) << 9));
#pragma unroll
        for (int q = 0; q < 4; ++q) gd[q] = gp[q * 64 + jhalf];
    }

    int p = 0;
    for (int s = 0; s < Tn; ++s) {
        const int tn = t + dt;

        // read h slice: 16 f16 = 2 x b128
        uint4 hA = ((const uint4*)&hls[p][0])[o * 2 + 0];
        uint4 hB = ((const uint4*)&hls[p][0])[o * 2 + 1];

        // prefetch next step's G
        unsigned gn[4] = {0u, 0u, 0u, 0u};
        if (s + 1 < Tn) {
            const unsigned* gp = (const unsigned*)(G + (((size_t)tn * Bn + b) << 9));
#pragma unroll
            for (int q = 0; q < 4; ++q) gn[q] = gp[q * 64 + jhalf];
        }

        unsigned hw[8] = {hA.x, hA.y, hA.z, hA.w, hB.x, hB.y, hB.z, hB.w};
        __half2 h2k[8];
#pragma unroll
        for (int kk = 0; kk < 8; ++kk) __builtin_memcpy(&h2k[kk], &hw[kk], 4);

        __half2 acc[8];
        const __half2 z2 = __floats2half2_rn(0.0f, 0.0f);
#pragma unroll
        for (int i = 0; i < 8; ++i) acc[i] = z2;
#pragma unroll
        for (int kk = 0; kk < 8; ++kk)
#pragma unroll
            for (int i = 0; i < 8; ++i)
                acc[i] = __hfma2(wpk[i][kk], h2k[kk], acc[i]);

        // finalize to f32 and reduce across the octet (DPP, no LDS)
        float dot[8];
#pragma unroll
        for (int i = 0; i < 8; ++i)
            dot[i] = __low2float(acc[i]) + __high2float(acc[i]);
#pragma unroll
        for (int i = 0; i < 8; ++i) {
            dot[i] = dpp_add<0xB1>(dot[i]);    // xor 1
            dot[i] = dpp_add<0x4E>(dot[i]);    // xor 2
            dot[i] = dpp_add<0x141>(dot[i]);   // half mirror (xor 4 within octet)
        }

        // pre-activations: dot + G (bf16 lo=j0, hi=j1)
        float pre0[4], pre1[4];
#pragma unroll
        for (int q = 0; q < 4; ++q) {
            float glo, ghi;
            unsigned lo = gd[q] << 16;
            unsigned hi = gd[q] & 0xffff0000u;
            __builtin_memcpy(&glo, &lo, 4);
            __builtin_memcpy(&ghi, &hi, 4);
            pre0[q] = dot[q] + glo;
            pre1[q] = dot[4 + q] + ghi;
        }

        // activations (replicated across octet; c0/c1 stay bit-identical)
        float i0 = sigf(pre0[0]), f0 = sigf(pre0[1]), g0 = tanhfast(pre0[2]), s0 = sigf(pre0[3]);
        c0 = f0 * c0 + i0 * g0;
        float h0 = s0 * tanhfast(c0);
        float i1 = sigf(pre1[0]), f1 = sigf(pre1[1]), g1 = tanhfast(pre1[2]), s1 = sigf(pre1[3]);
        c1 = f1 * c1 + i1 * g1;
        float h1 = s1 * tanhfast(c1);

        // one lane per octet writes the j-pair: LDS (f16) + global (bf16)
        if (o == 0) {
            __half2 hh = __floats2half2_rn(h0, h1);
            unsigned hw2;
            __builtin_memcpy(&hw2, &hh, 4);
            hls[1 - p][jhalf] = hw2;
            unsigned bw = (unsigned)f2bf(h0) | ((unsigned)f2bf(h1) << 16);
            ((unsigned*)(ho + (((size_t)t * Bn + b) << 7)))[jhalf] = bw;
        }
        __syncthreads();

#pragma unroll
        for (int q = 0; q < 4; ++q) gd[q] = gn[q];
        t = tn;
        p ^= 1;
    }
}

// =====================================================================
// K3: feats[t][b][k] = h_f[t,b,:].w_out[k][0:128] + h_b[t,b,:].w_out[k][128:256] + b_out[k]
// One thread per row (t*64+b); w_out transposed+padded in LDS.
// =====================================================================
__global__ __launch_bounds__(256) void k_feats(
    const unsigned short* __restrict__ h_f, const unsigned short* __restrict__ h_b,
    const float* __restrict__ w_out, const float* __restrict__ b_out,
    float* __restrict__ feats)
{
    __shared__ float wl[256][12];   // [j][k], k padded to 12
    __shared__ float bl[12];
    const int tid = threadIdx.x;
#pragma unroll
    for (int s = 0; s < 9; ++s) wl[tid][s] = w_out[s * 256 + tid];
#pragma unroll
    for (int s = 9; s < 12; ++s) wl[tid][s] = 0.0f;
    if (tid < 12) bl[tid] = (tid < 9) ? b_out[tid] : 0.0f;
    __syncthreads();

    const int r = blockIdx.x * 256 + tid;
    const unsigned short* hfr = h_f + (size_t)r * 128;
    const unsigned short* hbr = h_b + (size_t)r * 128;
    float acc[12];
#pragma unroll
    for (int k = 0; k < 12; ++k) acc[k] = bl[k];

    for (int ch = 0; ch < 32; ++ch) {
        const unsigned short* src = (ch < 16) ? (hfr + ch * 8) : (hbr + (ch - 16) * 8);
        uint4 hv = *(const uint4*)src;
        unsigned int hw0 = hv.x, hw1 = hv.y, hw2 = hv.z, hw3 = hv.w;
        const int jb = ch * 8;
#pragma unroll
        for (int q = 0; q < 8; ++q) {
            unsigned int word = (q < 2) ? hw0 : ((q < 4) ? hw1 : ((q < 6) ? hw2 : hw3));
            unsigned short hs = (q & 1) ? (unsigned short)(word >> 16) : (unsigned short)(word & 0xffff);
            float hf = bf2f(hs);
            const float* wrp = &wl[jb + q][0];
            float4 w0 = *(const float4*)(wrp);
            float4 w1 = *(const float4*)(wrp + 4);
            float4 w2 = *(const float4*)(wrp + 8);
            acc[0] += hf * w0.x; acc[1] += hf * w0.y; acc[2] += hf * w0.z; acc[3] += hf * w0.w;
            acc[4] += hf * w1.x; acc[5] += hf * w1.y; acc[6] += hf * w1.z; acc[7] += hf * w1.w;
            acc[8] += hf * w2.x; acc[9] += hf * w2.y; acc[10] += hf * w2.z; acc[11] += hf * w2.w;
        }
    }
    float* fr = feats + (size_t)r * 9;
#pragma unroll
    for (int k = 0; k < 9; ++k) fr[k] = acc[k];
}

// =====================================================================
// K4: Viterbi DP + backtrace. One wave (64 threads) per batch, wave-synchronous.
// bp rows padded to 16B so the backtrace load address is tag-independent.
// =====================================================================
__global__ __launch_bounds__(64) void k_viterbi(
    const float* __restrict__ feats, const float* __restrict__ trans,
    float* __restrict__ out)
{
    __shared__ __align__(16) unsigned char bp[1024 * 16];   // 16 KB
    __shared__ float fl[1024 * 9];                          // 36 KB
    __shared__ float dl[12];
    __shared__ unsigned char pt[1024];

    const int b = blockIdx.x, tid = threadIdx.x;

    // preload this batch's feats into LDS
    for (int i = tid; i < 9216; i += 64) {
        int t = i / 9;
        int n = i - t * 9;
        fl[i] = feats[((size_t)t * 64 + b) * 9 + n];
    }

    float tr[9];
    float trs = -3.0e38f;
    if (tid < 9) {
#pragma unroll
        for (int p = 0; p < 9; ++p) tr[p] = trans[tid * 9 + p];
        trs = trans[8 * 9 + tid];
    }
    if (tid < 12) dl[tid] = (tid == 7) ? 0.0f : NEGV;
    __syncthreads();

    if (tid < 9) {
        for (int t = 0; t < 1024; ++t) {
            float4 d0 = *(const float4*)&dl[0];
            float4 d1 = *(const float4*)&dl[4];
            float d8 = dl[8];
            float dv0 = d0.x, dv1 = d0.y, dv2 = d0.z, dv3 = d0.w;
            float dv4 = d1.x, dv5 = d1.y, dv6 = d1.z, dv7 = d1.w;
            float m = dv0 + tr[0]; int am = 0;
            float v;
            v = dv1 + tr[1]; if (v > m) { m = v; am = 1; }
            v = dv2 + tr[2]; if (v > m) { m = v; am = 2; }
            v = dv3 + tr[3]; if (v > m) { m = v; am = 3; }
            v = dv4 + tr[4]; if (v > m) { m = v; am = 4; }
            v = dv5 + tr[5]; if (v > m) { m = v; am = 5; }
            v = dv6 + tr[6]; if (v > m) { m = v; am = 6; }
            v = dv7 + tr[7]; if (v > m) { m = v; am = 7; }
            v = d8  + tr[8]; if (v > m) { m = v; am = 8; }
            float nd = m + fl[t * 9 + tid];
            dl[tid] = nd;
            bp[t * 16 + tid] = (unsigned char)am;
        }
    }
    // terminal: tv = delta[n] + trans[STOP][n]
    float tv = (tid < 9) ? (dl[tid] + trs) : -3.0e38f;
    int bi = tid;
#pragma unroll
    for (int off = 8; off >= 1; off >>= 1) {
        float ov = __shfl_down(tv, off, 64);
        int oi = __shfl_down(bi, off, 64);
        if (ov > tv || (ov == tv && oi < bi)) { tv = ov; bi = oi; }
    }
    int best = __shfl(bi, 0, 64);
    if (tid == 0) out[b] = tv;

    if (tid == 0) {
        int tag = best;
        for (int t0 = 1023; t0 >= 0; t0 -= 8) {
            uint4 rows[8];
#pragma unroll
            for (int i = 0; i < 8; ++i) rows[i] = *(const uint4*)&bp[(t0 - i) * 16];
#pragma unroll
            for (int i = 0; i < 8; ++i) {
                pt[t0 - i] = (unsigned char)tag;
                uint4 rw = rows[i];
                unsigned int sel = (unsigned int)tag >> 2;
                unsigned int word = (sel == 0) ? rw.x : ((sel == 1) ? rw.y : rw.z);
                tag = (int)((word >> ((tag & 3) * 8)) & 0xffu);
            }
        }
    }
    // coalesced path write (as float values)
    for (int i = tid; i < 1024; i += 64) {
        out[64 + b * 1024 + i] = (float)pt[i];
    }
}

// =====================================================================
extern "C" void kernel_launch(void* const* d_in, const int* in_sizes, int n_in,
                              void* d_out, int out_size, void* d_ws, size_t ws_size,
                              hipStream_t stream) {
    const int*   sent   = (const int*)d_in[0];
    const float* embed  = (const float*)d_in[1];
    const float* w_ih_f = (const float*)d_in[2];
    const float* w_hh_f = (const float*)d_in[3];
    const float* b_ih_f = (const float*)d_in[4];
    const float* b_hh_f = (const float*)d_in[5];
    const float* w_ih_b = (const float*)d_in[6];
    const float* w_hh_b = (const float*)d_in[7];
    const float* b_ih_b = (const float*)d_in[8];
    const float* b_hh_b = (const float*)d_in[9];
    const float* w_out  = (const float*)d_in[10];
    const float* b_out  = (const float*)d_in[11];
    const float* trans  = (const float*)d_in[12];
    float* out = (float*)d_out;

    // workspace layout (bf16 G + h, fp32 feats): ~162.4 MB
    unsigned short* G_f = (unsigned short*)d_ws;
    unsigned short* G_b = G_f + (size_t)Tn * Bn * G4;      // +33.5M elems
    unsigned short* h_f = G_b + (size_t)Tn * Bn * G4;
    unsigned short* h_b = h_f + (size_t)Tn * Bn * 128;
    float* feats = (float*)(h_b + (size_t)Tn * Bn * 128);

    k_inproj<<<dim3(512, 4, 2), 256, 0, stream>>>(sent, embed,
        w_ih_f, b_ih_f, b_hh_f, w_ih_b, b_ih_b, b_hh_b, G_f, G_b);
    k_lstm<<<dim3(64, 2), 512, 0, stream>>>(w_hh_f, w_hh_b, G_f, G_b, h_f, h_b);
    k_feats<<<256, 256, 0, stream>>>(h_f, h_b, w_out, b_out, feats);
    k_viterbi<<<64, 64, 0, stream>>>(feats, trans, out);
}

// Round 4
// 1305.345 us; speedup vs baseline: 1.3390x; 1.3390x over previous
//
#include <hip/hip_runtime.h>
#include <hip/hip_bf16.h>

#define Tn 1024
#define Bn 64
#define En 128
#define G4 512
#define NEGV -10000.0f

typedef _Float16 h2v __attribute__((ext_vector_type(2)));
typedef short bh8 __attribute__((ext_vector_type(8)));
typedef float fl4 __attribute__((ext_vector_type(4)));

// ---------- bf16 helpers ----------
__device__ __forceinline__ float bf2f(unsigned short u) {
    unsigned int v = ((unsigned int)u) << 16;
    float f;
    __builtin_memcpy(&f, &v, 4);
    return f;
}
__device__ __forceinline__ unsigned short f2bf(float f) {
    unsigned int u;
    __builtin_memcpy(&u, &f, 4);
    u = (u + 0x7fffu + ((u >> 16) & 1u)) >> 16;
    return (unsigned short)u;
}

// DPP cross-lane add within quad (pure VALU). 0xB1=xor1, 0x4E=xor2.
template <int CTRL>
__device__ __forceinline__ float dpp_add(float a) {
    int v;
    __builtin_memcpy(&v, &a, 4);
    int m = __builtin_amdgcn_update_dpp(0, v, CTRL, 0xf, 0xf, true);
    float b;
    __builtin_memcpy(&b, &m, 4);
    return a + b;
}

__device__ __forceinline__ float sigf(float x) { return 1.0f / (1.0f + __expf(-x)); }
__device__ __forceinline__ float tanhfast(float x) { return 1.0f - 2.0f / (1.0f + __expf(2.0f * x)); }

// lgkm-only barrier: LDS visibility without draining vmcnt (avoids the
// compiler's s_waitcnt vmcnt(0) before s_barrier in __syncthreads()).
// imm 0xC07F = vmcnt(63) expcnt(7) lgkmcnt(0).
__device__ __forceinline__ void barrier_lds_only() {
    __builtin_amdgcn_s_waitcnt(0xC07F);
    __builtin_amdgcn_s_barrier();
}

// =====================================================================
// K1: input projection via bf16 MFMA. G[t*64+b][g] = embed[tok].w_ih[g] + biases
// GEMM M=65536, N=512, K=128. WG 256 = 4 waves; C-tile 128x128;
// wave w covers n-slice 32 (8 m-tiles x 2 n-tiles x 4 k-steps = 64 MFMA).
// =====================================================================
__global__ __launch_bounds__(256) void k_inproj(
    const int* __restrict__ sent, const float* __restrict__ embed,
    const float* __restrict__ w_ih_f, const float* __restrict__ b_ih_f, const float* __restrict__ b_hh_f,
    const float* __restrict__ w_ih_b, const float* __restrict__ b_ih_b, const float* __restrict__ b_hh_b,
    unsigned short* __restrict__ G_f, unsigned short* __restrict__ G_b)
{
    __shared__ unsigned short Asm[128][136];   // padded: 272B rows (16B-aligned, 2-way banks)
    __shared__ unsigned short Bsm[128][136];
    const int tid = threadIdx.x;
    const int dir = blockIdx.z;
    const float* w_ih = dir ? w_ih_b : w_ih_f;
    const float* bi   = dir ? b_ih_b : b_ih_f;
    const float* bh   = dir ? b_hh_b : b_hh_f;
    unsigned short* Gout = dir ? G_b : G_f;

    const int mt = blockIdx.x, nt = blockIdx.y;
    const int r0 = mt * 128, n0 = nt * 128;

    // ---- stage A (embed gather) and B (w_ih rows) as bf16 ----
    const int srow = tid >> 1;
    const int ch = (tid & 1) * 64;
    {
        const int rg = r0 + srow;
        const int tt = rg >> 6, bb = rg & 63;
        const int tok = sent[bb * Tn + tt];
        const float* ar = embed + (size_t)tok * En + ch;
        const float* br = w_ih + (size_t)(n0 + srow) * En + ch;
#pragma unroll
        for (int i = 0; i < 64; i += 4) {
            float4 v = *(const float4*)(ar + i);
            *(unsigned*)&Asm[srow][ch + i]     = (unsigned)f2bf(v.x) | ((unsigned)f2bf(v.y) << 16);
            *(unsigned*)&Asm[srow][ch + i + 2] = (unsigned)f2bf(v.z) | ((unsigned)f2bf(v.w) << 16);
            float4 u = *(const float4*)(br + i);
            *(unsigned*)&Bsm[srow][ch + i]     = (unsigned)f2bf(u.x) | ((unsigned)f2bf(u.y) << 16);
            *(unsigned*)&Bsm[srow][ch + i + 2] = (unsigned)f2bf(u.z) | ((unsigned)f2bf(u.w) << 16);
        }
    }
    __syncthreads();

    // ---- MFMA ----
    const int w = tid >> 6, lane = tid & 63;
    const int ln = lane & 15, lq = lane >> 4;
    const int nwb = w * 32;

    fl4 acc[8][2];
#pragma unroll
    for (int mi = 0; mi < 8; ++mi)
#pragma unroll
        for (int ni = 0; ni < 2; ++ni) acc[mi][ni] = (fl4){0.f, 0.f, 0.f, 0.f};

#pragma unroll
    for (int kt = 0; kt < 4; ++kt) {
        const int kc = kt * 32 + lq * 8;
        bh8 a[8], bf[2];
#pragma unroll
        for (int mi = 0; mi < 8; ++mi) a[mi] = *(const bh8*)&Asm[mi * 16 + ln][kc];
#pragma unroll
        for (int ni = 0; ni < 2; ++ni) bf[ni] = *(const bh8*)&Bsm[nwb + ni * 16 + ln][kc];
#pragma unroll
        for (int mi = 0; mi < 8; ++mi)
#pragma unroll
            for (int ni = 0; ni < 2; ++ni)
                acc[mi][ni] = __builtin_amdgcn_mfma_f32_16x16x32_bf16(a[mi], bf[ni], acc[mi][ni], 0, 0, 0);
    }

    // ---- epilogue: bias + bf16 store ----
    float bias[2];
#pragma unroll
    for (int ni = 0; ni < 2; ++ni) {
        int n = n0 + nwb + ni * 16 + ln;
        bias[ni] = bi[n] + bh[n];
    }
#pragma unroll
    for (int mi = 0; mi < 8; ++mi)
#pragma unroll
        for (int ni = 0; ni < 2; ++ni) {
            const int n = n0 + nwb + ni * 16 + ln;
#pragma unroll
            for (int rg = 0; rg < 4; ++rg) {
                const int m = mi * 16 + lq * 4 + rg;
                const size_t r = (size_t)(r0 + m);         // == t*64+b
                Gout[(r << 9) + n] = f2bf(acc[mi][ni][rg] + bias[ni]);
            }
        }
}

// =====================================================================
// K2: LSTM recurrence. One WG per (batch, dir), 512 threads = 8 waves.
// Quad (4 lanes) owns h-elem j: lane ks=lane&3 computes all 4 gate dots over
// k-slice [32ks,32ks+32), reduced with 2 DPP stages. Octet g: j0=wv*16+2g+jsel.
// G refilled in 8-step blocks (lane o holds step-offset o), double-buffered,
// distributed per step via shfl. h double-buffered f16 in LDS.
// Barriers are lgkm-only -> outstanding global ops never drain at the barrier.
// =====================================================================
__global__ __launch_bounds__(512, 2) void k_lstm(
    const float* __restrict__ whh_f, const float* __restrict__ whh_b,
    const unsigned short* __restrict__ G_f, const unsigned short* __restrict__ G_b,
    unsigned short* __restrict__ h_f, unsigned short* __restrict__ h_b)
{
    const int tid = threadIdx.x;
    const int wv = tid >> 6;
    const int lane = tid & 63;
    const int g = lane >> 3;          // octet within wave
    const int o = lane & 7;           // member within octet
    const int ks = lane & 3;          // k-slice selector
    const int jsel = (lane >> 2) & 1; // which j of the octet's pair
    const int b = blockIdx.x;
    const int dir = blockIdx.y;
    const float* whh = dir ? whh_b : whh_f;
    const unsigned* Gd = (const unsigned*)(dir ? G_b : G_f);
    unsigned short* ho = dir ? h_b : h_f;

    const int j = wv * 16 + 2 * g + jsel;   // h index this lane computes
    const int jh = wv * 8 + g;              // dword index of the octet's (j0,j1) pair

    __shared__ __align__(16) unsigned hls[2][64];   // 2 x 128 f16

    // weights: 4 gate rows for j, k in [32ks, 32ks+32) -> 64 h2v = 64 VGPRs
    h2v wq[4][16];
#pragma unroll
    for (int q = 0; q < 4; ++q) {
        const float2* wr = (const float2*)(whh + (size_t)(q * 128 + j) * 128 + ks * 32);
#pragma unroll
        for (int kk = 0; kk < 16; ++kk) {
            float2 wv2 = wr[kk];
            h2v hv; hv[0] = (_Float16)wv2.x; hv[1] = (_Float16)wv2.y;
            wq[q][kk] = hv;
        }
    }

    if (tid < 128) ((unsigned*)hls)[tid] = 0u;
    float c = 0.0f;
    __syncthreads();

    const int dt = dir ? -1 : 1;
    int t = dir ? (Tn - 1) : 0;

    // G double-buffered 8-step blocks: lane o loads octet's 4 q-dwords for step blk*8+o
    unsigned gcur[4], gnxt[4];
    {
        int sb = o;                       // block 0
        int tt = dir ? (Tn - 1 - sb) : sb;
        const unsigned* gp = Gd + (((size_t)tt * Bn + b) << 8);
#pragma unroll
        for (int q = 0; q < 4; ++q) gcur[q] = gp[q * 64 + jh];
        sb = 8 + o;                       // block 1
        tt = dir ? (Tn - 1 - sb) : sb;
        gp = Gd + (((size_t)tt * Bn + b) << 8);
#pragma unroll
        for (int q = 0; q < 4; ++q) gnxt[q] = gp[q * 64 + jh];
    }

    int p = 0;
    for (int s = 0; s < Tn; ++s) {
        if (s && !(s & 7)) {              // block boundary: rotate + refill
#pragma unroll
            for (int q = 0; q < 4; ++q) gcur[q] = gnxt[q];
            const int nb = (s >> 3) + 1;
            if (nb < (Tn >> 3)) {
                const int sb = nb * 8 + o;
                const int tt = dir ? (Tn - 1 - sb) : sb;
                const unsigned* gp = Gd + (((size_t)tt * Bn + b) << 8);
#pragma unroll
                for (int q = 0; q < 4; ++q) gnxt[q] = gp[q * 64 + jh];
            }
        }

        // this step's G dwords: held by lane (octet_base + s%8)
        const int srcl = (lane & 56) | (s & 7);
        unsigned gq[4];
#pragma unroll
        for (int q = 0; q < 4; ++q) gq[q] = __shfl(gcur[q], srcl, 64);

        // h slice: 32 f16 = 4 x b128 from LDS
        const uint4* hb = (const uint4*)&hls[p][ks * 16];
        uint4 h0 = hb[0], h1 = hb[1], h2 = hb[2], h3 = hb[3];
        unsigned hw[16] = {h0.x, h0.y, h0.z, h0.w, h1.x, h1.y, h1.z, h1.w,
                           h2.x, h2.y, h2.z, h2.w, h3.x, h3.y, h3.z, h3.w};
        h2v hx[16];
#pragma unroll
        for (int kk = 0; kk < 16; ++kk) __builtin_memcpy(&hx[kk], &hw[kk], 4);

        // 4 gate dots over this lane's k-slice
#if __has_builtin(__builtin_amdgcn_fdot2)
        float dq[4] = {0.f, 0.f, 0.f, 0.f};
#pragma unroll
        for (int kk = 0; kk < 16; ++kk)
#pragma unroll
            for (int q = 0; q < 4; ++q)
                dq[q] = __builtin_amdgcn_fdot2(wq[q][kk], hx[kk], dq[q], false);
#else
        h2v accq[4];
#pragma unroll
        for (int q = 0; q < 4; ++q) { accq[q][0] = (_Float16)0; accq[q][1] = (_Float16)0; }
#pragma unroll
        for (int kk = 0; kk < 16; ++kk)
#pragma unroll
            for (int q = 0; q < 4; ++q)
                accq[q] += wq[q][kk] * hx[kk];
        float dq[4];
#pragma unroll
        for (int q = 0; q < 4; ++q) dq[q] = (float)accq[q][0] + (float)accq[q][1];
#endif

        // reduce across the quad (2 DPP stages) -> full dots replicated in quad
#pragma unroll
        for (int q = 0; q < 4; ++q) {
            dq[q] = dpp_add<0xB1>(dq[q]);
            dq[q] = dpp_add<0x4E>(dq[q]);
        }

        // pre-activations: + G (bf16 half selected by jsel)
        float pre[4];
#pragma unroll
        for (int q = 0; q < 4; ++q) {
            unsigned u = jsel ? (gq[q] & 0xffff0000u) : (gq[q] << 16);
            float gf;
            __builtin_memcpy(&gf, &u, 4);
            pre[q] = dq[q] + gf;
        }

        // activations (replicated across quad; c stays bit-identical)
        float iv = sigf(pre[0]), fv = sigf(pre[1]), gv = tanhfast(pre[2]), ov = sigf(pre[3]);
        c = fv * c + iv * gv;
        float hn = ov * tanhfast(c);

        // one lane per quad writes h: LDS (f16) + global (bf16)
        if (ks == 0) {
            _Float16 hf = (_Float16)hn;
            unsigned short hu;
            __builtin_memcpy(&hu, &hf, 2);
            ((unsigned short*)&hls[1 - p][0])[j] = hu;
            ho[(((size_t)t * Bn + b) << 7) + j] = f2bf(hn);
        }
        barrier_lds_only();
        t += dt;
        p ^= 1;
    }
}

// =====================================================================
// K3: feats[t][b][k] = h_f[t,b,:].w_out[k][0:128] + h_b[t,b,:].w_out[k][128:256] + b_out[k]
// =====================================================================
__global__ __launch_bounds__(256) void k_feats(
    const unsigned short* __restrict__ h_f, const unsigned short* __restrict__ h_b,
    const float* __restrict__ w_out, const float* __restrict__ b_out,
    float* __restrict__ feats)
{
    __shared__ float wl[256][12];   // [j][k], k padded to 12
    __shared__ float bl[12];
    const int tid = threadIdx.x;
#pragma unroll
    for (int s = 0; s < 9; ++s) wl[tid][s] = w_out[s * 256 + tid];
#pragma unroll
    for (int s = 9; s < 12; ++s) wl[tid][s] = 0.0f;
    if (tid < 12) bl[tid] = (tid < 9) ? b_out[tid] : 0.0f;
    __syncthreads();

    const int r = blockIdx.x * 256 + tid;
    const unsigned short* hfr = h_f + (size_t)r * 128;
    const unsigned short* hbr = h_b + (size_t)r * 128;
    float acc[12];
#pragma unroll
    for (int k = 0; k < 12; ++k) acc[k] = bl[k];

    for (int ch = 0; ch < 32; ++ch) {
        const unsigned short* src = (ch < 16) ? (hfr + ch * 8) : (hbr + (ch - 16) * 8);
        uint4 hv = *(const uint4*)src;
        unsigned int hw0 = hv.x, hw1 = hv.y, hw2 = hv.z, hw3 = hv.w;
        const int jb = ch * 8;
#pragma unroll
        for (int q = 0; q < 8; ++q) {
            unsigned int word = (q < 2) ? hw0 : ((q < 4) ? hw1 : ((q < 6) ? hw2 : hw3));
            unsigned short hs = (q & 1) ? (unsigned short)(word >> 16) : (unsigned short)(word & 0xffff);
            float hf = bf2f(hs);
            const float* wrp = &wl[jb + q][0];
            float4 w0 = *(const float4*)(wrp);
            float4 w1 = *(const float4*)(wrp + 4);
            float4 w2 = *(const float4*)(wrp + 8);
            acc[0] += hf * w0.x; acc[1] += hf * w0.y; acc[2] += hf * w0.z; acc[3] += hf * w0.w;
            acc[4] += hf * w1.x; acc[5] += hf * w1.y; acc[6] += hf * w1.z; acc[7] += hf * w1.w;
            acc[8] += hf * w2.x; acc[9] += hf * w2.y; acc[10] += hf * w2.z; acc[11] += hf * w2.w;
        }
    }
    float* fr = feats + (size_t)r * 9;
#pragma unroll
    for (int k = 0; k < 9; ++k) fr[k] = acc[k];
}

// =====================================================================
// K4: Viterbi DP + backtrace. One wave per batch, wave-synchronous.
// =====================================================================
__global__ __launch_bounds__(64) void k_viterbi(
    const float* __restrict__ feats, const float* __restrict__ trans,
    float* __restrict__ out)
{
    __shared__ __align__(16) unsigned char bp[1024 * 16];   // 16 KB
    __shared__ float fl[1024 * 9];                          // 36 KB
    __shared__ float dl[12];
    __shared__ unsigned char pt[1024];

    const int b = blockIdx.x, tid = threadIdx.x;

    for (int i = tid; i < 9216; i += 64) {
        int t = i / 9;
        int n = i - t * 9;
        fl[i] = feats[((size_t)t * 64 + b) * 9 + n];
    }

    float tr[9];
    float trs = -3.0e38f;
    if (tid < 9) {
#pragma unroll
        for (int p = 0; p < 9; ++p) tr[p] = trans[tid * 9 + p];
        trs = trans[8 * 9 + tid];
    }
    if (tid < 12) dl[tid] = (tid == 7) ? 0.0f : NEGV;
    __syncthreads();

    if (tid < 9) {
        for (int t = 0; t < 1024; ++t) {
            float4 d0 = *(const float4*)&dl[0];
            float4 d1 = *(const float4*)&dl[4];
            float d8 = dl[8];
            float dv0 = d0.x, dv1 = d0.y, dv2 = d0.z, dv3 = d0.w;
            float dv4 = d1.x, dv5 = d1.y, dv6 = d1.z, dv7 = d1.w;
            float m = dv0 + tr[0]; int am = 0;
            float v;
            v = dv1 + tr[1]; if (v > m) { m = v; am = 1; }
            v = dv2 + tr[2]; if (v > m) { m = v; am = 2; }
            v = dv3 + tr[3]; if (v > m) { m = v; am = 3; }
            v = dv4 + tr[4]; if (v > m) { m = v; am = 4; }
            v = dv5 + tr[5]; if (v > m) { m = v; am = 5; }
            v = dv6 + tr[6]; if (v > m) { m = v; am = 6; }
            v = dv7 + tr[7]; if (v > m) { m = v; am = 7; }
            v = d8  + tr[8]; if (v > m) { m = v; am = 8; }
            float nd = m + fl[t * 9 + tid];
            dl[tid] = nd;
            bp[t * 16 + tid] = (unsigned char)am;
        }
    }
    float tv = (tid < 9) ? (dl[tid] + trs) : -3.0e38f;
    int bi = tid;
#pragma unroll
    for (int off = 8; off >= 1; off >>= 1) {
        float ov = __shfl_down(tv, off, 64);
        int oi = __shfl_down(bi, off, 64);
        if (ov > tv || (ov == tv && oi < bi)) { tv = ov; bi = oi; }
    }
    int best = __shfl(bi, 0, 64);
    if (tid == 0) out[b] = tv;

    if (tid == 0) {
        int tag = best;
        for (int t0 = 1023; t0 >= 0; t0 -= 8) {
            uint4 rows[8];
#pragma unroll
            for (int i = 0; i < 8; ++i) rows[i] = *(const uint4*)&bp[(t0 - i) * 16];
#pragma unroll
            for (int i = 0; i < 8; ++i) {
                pt[t0 - i] = (unsigned char)tag;
                uint4 rw = rows[i];
                unsigned int sel = (unsigned int)tag >> 2;
                unsigned int word = (sel == 0) ? rw.x : ((sel == 1) ? rw.y : rw.z);
                tag = (int)((word >> ((tag & 3) * 8)) & 0xffu);
            }
        }
    }
    for (int i = tid; i < 1024; i += 64) {
        out[64 + b * 1024 + i] = (float)pt[i];
    }
}

// =====================================================================
extern "C" void kernel_launch(void* const* d_in, const int* in_sizes, int n_in,
                              void* d_out, int out_size, void* d_ws, size_t ws_size,
                              hipStream_t stream) {
    const int*   sent   = (const int*)d_in[0];
    const float* embed  = (const float*)d_in[1];
    const float* w_ih_f = (const float*)d_in[2];
    const float* w_hh_f = (const float*)d_in[3];
    const float* b_ih_f = (const float*)d_in[4];
    const float* b_hh_f = (const float*)d_in[5];
    const float* w_ih_b = (const float*)d_in[6];
    const float* w_hh_b = (const float*)d_in[7];
    const float* b_ih_b = (const float*)d_in[8];
    const float* b_hh_b = (const float*)d_in[9];
    const float* w_out  = (const float*)d_in[10];
    const float* b_out  = (const float*)d_in[11];
    const float* trans  = (const float*)d_in[12];
    float* out = (float*)d_out;

    unsigned short* G_f = (unsigned short*)d_ws;
    unsigned short* G_b = G_f + (size_t)Tn * Bn * G4;
    unsigned short* h_f = G_b + (size_t)Tn * Bn * G4;
    unsigned short* h_b = h_f + (size_t)Tn * Bn * 128;
    float* feats = (float*)(h_b + (size_t)Tn * Bn * 128);

    k_inproj<<<dim3(512, 4, 2), 256, 0, stream>>>(sent, embed,
        w_ih_f, b_ih_f, b_hh_f, w_ih_b, b_ih_b, b_hh_b, G_f, G_b);
    k_lstm<<<dim3(64, 2), 512, 0, stream>>>(w_hh_f, w_hh_b, G_f, G_b, h_f, h_b);
    k_feats<<<256, 256, 0, stream>>>(h_f, h_b, w_out, b_out, feats);
    k_viterbi<<<64, 64, 0, stream>>>(feats, trans, out);
}

// Round 5
// 1301.852 us; speedup vs baseline: 1.3426x; 1.0027x over previous
//
#include <hip/hip_runtime.h>
#include <hip/hip_bf16.h>

#define Tn 1024
#define Bn 64
#define En 128
#define G4 512
#define NEGV -10000.0f

typedef _Float16 h2v __attribute__((ext_vector_type(2)));
typedef short bh8 __attribute__((ext_vector_type(8)));
typedef float fl4 __attribute__((ext_vector_type(4)));
typedef unsigned u4v __attribute__((ext_vector_type(4)));

// ---------- bf16 helpers ----------
__device__ __forceinline__ float bf2f(unsigned short u) {
    unsigned int v = ((unsigned int)u) << 16;
    float f;
    __builtin_memcpy(&f, &v, 4);
    return f;
}
__device__ __forceinline__ unsigned short f2bf(float f) {
    unsigned int u;
    __builtin_memcpy(&u, &f, 4);
    u = (u + 0x7fffu + ((u >> 16) & 1u)) >> 16;
    return (unsigned short)u;
}

// DPP cross-lane add within quad (pure VALU). 0xB1=xor1, 0x4E=xor2.
template <int CTRL>
__device__ __forceinline__ float dpp_add(float a) {
    int v;
    __builtin_memcpy(&v, &a, 4);
    int m = __builtin_amdgcn_update_dpp(0, v, CTRL, 0xf, 0xf, true);
    float b;
    __builtin_memcpy(&b, &m, 4);
    return a + b;
}

__device__ __forceinline__ float sigf(float x) { return 1.0f / (1.0f + __expf(-x)); }
__device__ __forceinline__ float tanhfast(float x) { return 1.0f - 2.0f / (1.0f + __expf(2.0f * x)); }

// lgkm-only barrier: LDS visibility without draining vmcnt.
// imm 0xC07F = vmcnt(63) expcnt(7) lgkmcnt(0).
__device__ __forceinline__ void barrier_lds_only() {
    __builtin_amdgcn_s_waitcnt(0xC07F);
    __builtin_amdgcn_s_barrier();
}

// =====================================================================
// K1: input projection via bf16 MFMA (unchanged from R4).
// =====================================================================
__global__ __launch_bounds__(256) void k_inproj(
    const int* __restrict__ sent, const float* __restrict__ embed,
    const float* __restrict__ w_ih_f, const float* __restrict__ b_ih_f, const float* __restrict__ b_hh_f,
    const float* __restrict__ w_ih_b, const float* __restrict__ b_ih_b, const float* __restrict__ b_hh_b,
    unsigned short* __restrict__ G_f, unsigned short* __restrict__ G_b)
{
    __shared__ unsigned short Asm[128][136];
    __shared__ unsigned short Bsm[128][136];
    const int tid = threadIdx.x;
    const int dir = blockIdx.z;
    const float* w_ih = dir ? w_ih_b : w_ih_f;
    const float* bi   = dir ? b_ih_b : b_ih_f;
    const float* bh   = dir ? b_hh_b : b_hh_f;
    unsigned short* Gout = dir ? G_b : G_f;

    const int mt = blockIdx.x, nt = blockIdx.y;
    const int r0 = mt * 128, n0 = nt * 128;

    const int srow = tid >> 1;
    const int ch = (tid & 1) * 64;
    {
        const int rg = r0 + srow;
        const int tt = rg >> 6, bb = rg & 63;
        const int tok = sent[bb * Tn + tt];
        const float* ar = embed + (size_t)tok * En + ch;
        const float* br = w_ih + (size_t)(n0 + srow) * En + ch;
#pragma unroll
        for (int i = 0; i < 64; i += 4) {
            float4 v = *(const float4*)(ar + i);
            *(unsigned*)&Asm[srow][ch + i]     = (unsigned)f2bf(v.x) | ((unsigned)f2bf(v.y) << 16);
            *(unsigned*)&Asm[srow][ch + i + 2] = (unsigned)f2bf(v.z) | ((unsigned)f2bf(v.w) << 16);
            float4 u = *(const float4*)(br + i);
            *(unsigned*)&Bsm[srow][ch + i]     = (unsigned)f2bf(u.x) | ((unsigned)f2bf(u.y) << 16);
            *(unsigned*)&Bsm[srow][ch + i + 2] = (unsigned)f2bf(u.z) | ((unsigned)f2bf(u.w) << 16);
        }
    }
    __syncthreads();

    const int w = tid >> 6, lane = tid & 63;
    const int ln = lane & 15, lq = lane >> 4;
    const int nwb = w * 32;

    fl4 acc[8][2];
#pragma unroll
    for (int mi = 0; mi < 8; ++mi)
#pragma unroll
        for (int ni = 0; ni < 2; ++ni) acc[mi][ni] = (fl4){0.f, 0.f, 0.f, 0.f};

#pragma unroll
    for (int kt = 0; kt < 4; ++kt) {
        const int kc = kt * 32 + lq * 8;
        bh8 a[8], bf[2];
#pragma unroll
        for (int mi = 0; mi < 8; ++mi) a[mi] = *(const bh8*)&Asm[mi * 16 + ln][kc];
#pragma unroll
        for (int ni = 0; ni < 2; ++ni) bf[ni] = *(const bh8*)&Bsm[nwb + ni * 16 + ln][kc];
#pragma unroll
        for (int mi = 0; mi < 8; ++mi)
#pragma unroll
            for (int ni = 0; ni < 2; ++ni)
                acc[mi][ni] = __builtin_amdgcn_mfma_f32_16x16x32_bf16(a[mi], bf[ni], acc[mi][ni], 0, 0, 0);
    }

    float bias[2];
#pragma unroll
    for (int ni = 0; ni < 2; ++ni) {
        int n = n0 + nwb + ni * 16 + ln;
        bias[ni] = bi[n] + bh[n];
    }
#pragma unroll
    for (int mi = 0; mi < 8; ++mi)
#pragma unroll
        for (int ni = 0; ni < 2; ++ni) {
            const int n = n0 + nwb + ni * 16 + ln;
#pragma unroll
            for (int rg = 0; rg < 4; ++rg) {
                const int m = mi * 16 + lq * 4 + rg;
                const size_t r = (size_t)(r0 + m);
                Gout[(r << 9) + n] = f2bf(acc[mi][ni][rg] + bias[ni]);
            }
        }
}

// =====================================================================
// K2: LSTM recurrence. R4 structure + WEIGHTS PINNED IN VGPRs via inline-asm.
// Quad (4 lanes) owns h-elem j; lane ks computes 4 gate dots over k-slice
// [32ks,32ks+32); 2 DPP stages reduce; G in 8-step shfl-distributed blocks;
// h double-buffered f16 in LDS; lgkm-only barriers.
// Weights: 16 x u4v = 64 VGPRs, asm-pinned each iteration so the allocator
// cannot rematerialize/reload them from memory inside the loop.
// =====================================================================
__global__ __launch_bounds__(512, 2) void k_lstm(
    const float* __restrict__ whh_f, const float* __restrict__ whh_b,
    const unsigned short* __restrict__ G_f, const unsigned short* __restrict__ G_b,
    unsigned short* __restrict__ h_f, unsigned short* __restrict__ h_b)
{
    const int tid = threadIdx.x;
    const int wv = tid >> 6;
    const int lane = tid & 63;
    const int g = lane >> 3;
    const int o = lane & 7;
    const int ks = lane & 3;
    const int jsel = (lane >> 2) & 1;
    const int b = blockIdx.x;
    const int dir = blockIdx.y;
    const float* whh = dir ? whh_b : whh_f;
    const unsigned* Gd = (const unsigned*)(dir ? G_b : G_f);
    unsigned short* ho = dir ? h_b : h_f;

    const int j = wv * 16 + 2 * g + jsel;
    const int jh = wv * 8 + g;

    __shared__ __align__(16) unsigned hls[2][64];

    // ---- weights: gate q, dword kk (16 per gate) -> wreg[q*4 + (kk>>2)][kk&3]
    u4v wr0, wr1, wr2, wr3, wr4, wr5, wr6, wr7, wr8, wr9, wr10, wr11, wr12, wr13, wr14, wr15;
    {
        u4v tmp[16];
#pragma unroll
        for (int q = 0; q < 4; ++q) {
            const float2* wp = (const float2*)(whh + (size_t)(q * 128 + j) * 128 + ks * 32);
#pragma unroll
            for (int kk = 0; kk < 16; ++kk) {
                float2 wv2 = wp[kk];
                h2v hv; hv[0] = (_Float16)wv2.x; hv[1] = (_Float16)wv2.y;
                unsigned u;
                __builtin_memcpy(&u, &hv, 4);
                tmp[q * 4 + (kk >> 2)][kk & 3] = u;
            }
        }
        wr0 = tmp[0];  wr1 = tmp[1];  wr2 = tmp[2];  wr3 = tmp[3];
        wr4 = tmp[4];  wr5 = tmp[5];  wr6 = tmp[6];  wr7 = tmp[7];
        wr8 = tmp[8];  wr9 = tmp[9];  wr10 = tmp[10]; wr11 = tmp[11];
        wr12 = tmp[12]; wr13 = tmp[13]; wr14 = tmp[14]; wr15 = tmp[15];
    }

    if (tid < 128) ((unsigned*)hls)[tid] = 0u;
    float c = 0.0f;
    __syncthreads();

    const int dt = dir ? -1 : 1;
    int t = dir ? (Tn - 1) : 0;

    unsigned gcur[4], gnxt[4];
    {
        int sb = o;
        int tt = dir ? (Tn - 1 - sb) : sb;
        const unsigned* gp = Gd + (((size_t)tt * Bn + b) << 8);
#pragma unroll
        for (int q = 0; q < 4; ++q) gcur[q] = gp[q * 64 + jh];
        sb = 8 + o;
        tt = dir ? (Tn - 1 - sb) : sb;
        gp = Gd + (((size_t)tt * Bn + b) << 8);
#pragma unroll
        for (int q = 0; q < 4; ++q) gnxt[q] = gp[q * 64 + jh];
    }

    int p = 0;
    for (int s = 0; s < Tn; ++s) {
        // Pin the 64 weight VGPRs: asm claims to read+modify them every
        // iteration, so the compiler cannot rematerialize them from memory.
        asm volatile("" : "+v"(wr0), "+v"(wr1), "+v"(wr2), "+v"(wr3),
                          "+v"(wr4), "+v"(wr5), "+v"(wr6), "+v"(wr7),
                          "+v"(wr8), "+v"(wr9), "+v"(wr10), "+v"(wr11),
                          "+v"(wr12), "+v"(wr13), "+v"(wr14), "+v"(wr15));

        if (s && !(s & 7)) {
#pragma unroll
            for (int q = 0; q < 4; ++q) gcur[q] = gnxt[q];
            const int nb = (s >> 3) + 1;
            if (nb < (Tn >> 3)) {
                const int sb = nb * 8 + o;
                const int tt = dir ? (Tn - 1 - sb) : sb;
                const unsigned* gp = Gd + (((size_t)tt * Bn + b) << 8);
#pragma unroll
                for (int q = 0; q < 4; ++q) gnxt[q] = gp[q * 64 + jh];
            }
        }

        const int srcl = (lane & 56) | (s & 7);
        unsigned gq[4];
#pragma unroll
        for (int q = 0; q < 4; ++q) gq[q] = __shfl(gcur[q], srcl, 64);

        const uint4* hb = (const uint4*)&hls[p][ks * 16];
        uint4 h0 = hb[0], h1 = hb[1], h2 = hb[2], h3 = hb[3];
        unsigned hw[16] = {h0.x, h0.y, h0.z, h0.w, h1.x, h1.y, h1.z, h1.w,
                           h2.x, h2.y, h2.z, h2.w, h3.x, h3.y, h3.z, h3.w};

        u4v wregs[16] = {wr0, wr1, wr2, wr3, wr4, wr5, wr6, wr7,
                         wr8, wr9, wr10, wr11, wr12, wr13, wr14, wr15};

        float dq[4] = {0.f, 0.f, 0.f, 0.f};
#pragma unroll
        for (int kk = 0; kk < 16; ++kk) {
            h2v hh;
            __builtin_memcpy(&hh, &hw[kk], 4);
#pragma unroll
            for (int q = 0; q < 4; ++q) {
                unsigned wu = wregs[q * 4 + (kk >> 2)][kk & 3];
                h2v ww;
                __builtin_memcpy(&ww, &wu, 4);
#if __has_builtin(__builtin_amdgcn_fdot2)
                dq[q] = __builtin_amdgcn_fdot2(ww, hh, dq[q], false);
#else
                dq[q] += (float)(ww[0] * hh[0]) + (float)(ww[1] * hh[1]);
#endif
            }
        }

#pragma unroll
        for (int q = 0; q < 4; ++q) {
            dq[q] = dpp_add<0xB1>(dq[q]);
            dq[q] = dpp_add<0x4E>(dq[q]);
        }

        float pre[4];
#pragma unroll
        for (int q = 0; q < 4; ++q) {
            unsigned u = jsel ? (gq[q] & 0xffff0000u) : (gq[q] << 16);
            float gf;
            __builtin_memcpy(&gf, &u, 4);
            pre[q] = dq[q] + gf;
        }

        float iv = sigf(pre[0]), fv = sigf(pre[1]), gv = tanhfast(pre[2]), ov = sigf(pre[3]);
        c = fv * c + iv * gv;
        float hn = ov * tanhfast(c);

        if (ks == 0) {
            _Float16 hf = (_Float16)hn;
            unsigned short hu;
            __builtin_memcpy(&hu, &hf, 2);
            ((unsigned short*)&hls[1 - p][0])[j] = hu;
            ho[(((size_t)t * Bn + b) << 7) + j] = f2bf(hn);
        }
        barrier_lds_only();
        t += dt;
        p ^= 1;
    }
}

// =====================================================================
// K3: feats (unchanged from R4).
// =====================================================================
__global__ __launch_bounds__(256) void k_feats(
    const unsigned short* __restrict__ h_f, const unsigned short* __restrict__ h_b,
    const float* __restrict__ w_out, const float* __restrict__ b_out,
    float* __restrict__ feats)
{
    __shared__ float wl[256][12];
    __shared__ float bl[12];
    const int tid = threadIdx.x;
#pragma unroll
    for (int s = 0; s < 9; ++s) wl[tid][s] = w_out[s * 256 + tid];
#pragma unroll
    for (int s = 9; s < 12; ++s) wl[tid][s] = 0.0f;
    if (tid < 12) bl[tid] = (tid < 9) ? b_out[tid] : 0.0f;
    __syncthreads();

    const int r = blockIdx.x * 256 + tid;
    const unsigned short* hfr = h_f + (size_t)r * 128;
    const unsigned short* hbr = h_b + (size_t)r * 128;
    float acc[12];
#pragma unroll
    for (int k = 0; k < 12; ++k) acc[k] = bl[k];

    for (int ch = 0; ch < 32; ++ch) {
        const unsigned short* src = (ch < 16) ? (hfr + ch * 8) : (hbr + (ch - 16) * 8);
        uint4 hv = *(const uint4*)src;
        unsigned int hw0 = hv.x, hw1 = hv.y, hw2 = hv.z, hw3 = hv.w;
        const int jb = ch * 8;
#pragma unroll
        for (int q = 0; q < 8; ++q) {
            unsigned int word = (q < 2) ? hw0 : ((q < 4) ? hw1 : ((q < 6) ? hw2 : hw3));
            unsigned short hs = (q & 1) ? (unsigned short)(word >> 16) : (unsigned short)(word & 0xffff);
            float hf = bf2f(hs);
            const float* wrp = &wl[jb + q][0];
            float4 w0 = *(const float4*)(wrp);
            float4 w1 = *(const float4*)(wrp + 4);
            float4 w2 = *(const float4*)(wrp + 8);
            acc[0] += hf * w0.x; acc[1] += hf * w0.y; acc[2] += hf * w0.z; acc[3] += hf * w0.w;
            acc[4] += hf * w1.x; acc[5] += hf * w1.y; acc[6] += hf * w1.z; acc[7] += hf * w1.w;
            acc[8] += hf * w2.x; acc[9] += hf * w2.y; acc[10] += hf * w2.z; acc[11] += hf * w2.w;
        }
    }
    float* fr = feats + (size_t)r * 9;
#pragma unroll
    for (int k = 0; k < 9; ++k) fr[k] = acc[k];
}

// =====================================================================
// K4: Viterbi (unchanged from R4).
// =====================================================================
__global__ __launch_bounds__(64) void k_viterbi(
    const float* __restrict__ feats, const float* __restrict__ trans,
    float* __restrict__ out)
{
    __shared__ __align__(16) unsigned char bp[1024 * 16];
    __shared__ float fl[1024 * 9];
    __shared__ float dl[12];
    __shared__ unsigned char pt[1024];

    const int b = blockIdx.x, tid = threadIdx.x;

    for (int i = tid; i < 9216; i += 64) {
        int t = i / 9;
        int n = i - t * 9;
        fl[i] = feats[((size_t)t * 64 + b) * 9 + n];
    }

    float tr[9];
    float trs = -3.0e38f;
    if (tid < 9) {
#pragma unroll
        for (int p = 0; p < 9; ++p) tr[p] = trans[tid * 9 + p];
        trs = trans[8 * 9 + tid];
    }
    if (tid < 12) dl[tid] = (tid == 7) ? 0.0f : NEGV;
    __syncthreads();

    if (tid < 9) {
        for (int t = 0; t < 1024; ++t) {
            float4 d0 = *(const float4*)&dl[0];
            float4 d1 = *(const float4*)&dl[4];
            float d8 = dl[8];
            float dv0 = d0.x, dv1 = d0.y, dv2 = d0.z, dv3 = d0.w;
            float dv4 = d1.x, dv5 = d1.y, dv6 = d1.z, dv7 = d1.w;
            float m = dv0 + tr[0]; int am = 0;
            float v;
            v = dv1 + tr[1]; if (v > m) { m = v; am = 1; }
            v = dv2 + tr[2]; if (v > m) { m = v; am = 2; }
            v = dv3 + tr[3]; if (v > m) { m = v; am = 3; }
            v = dv4 + tr[4]; if (v > m) { m = v; am = 4; }
            v = dv5 + tr[5]; if (v > m) { m = v; am = 5; }
            v = dv6 + tr[6]; if (v > m) { m = v; am = 6; }
            v = dv7 + tr[7]; if (v > m) { m = v; am = 7; }
            v = d8  + tr[8]; if (v > m) { m = v; am = 8; }
            float nd = m + fl[t * 9 + tid];
            dl[tid] = nd;
            bp[t * 16 + tid] = (unsigned char)am;
        }
    }
    float tv = (tid < 9) ? (dl[tid] + trs) : -3.0e38f;
    int bi = tid;
#pragma unroll
    for (int off = 8; off >= 1; off >>= 1) {
        float ov = __shfl_down(tv, off, 64);
        int oi = __shfl_down(bi, off, 64);
        if (ov > tv || (ov == tv && oi < bi)) { tv = ov; bi = oi; }
    }
    int best = __shfl(bi, 0, 64);
    if (tid == 0) out[b] = tv;

    if (tid == 0) {
        int tag = best;
        for (int t0 = 1023; t0 >= 0; t0 -= 8) {
            uint4 rows[8];
#pragma unroll
            for (int i = 0; i < 8; ++i) rows[i] = *(const uint4*)&bp[(t0 - i) * 16];
#pragma unroll
            for (int i = 0; i < 8; ++i) {
                pt[t0 - i] = (unsigned char)tag;
                uint4 rw = rows[i];
                unsigned int sel = (unsigned int)tag >> 2;
                unsigned int word = (sel == 0) ? rw.x : ((sel == 1) ? rw.y : rw.z);
                tag = (int)((word >> ((tag & 3) * 8)) & 0xffu);
            }
        }
    }
    for (int i = tid; i < 1024; i += 64) {
        out[64 + b * 1024 + i] = (float)pt[i];
    }
}

// =====================================================================
extern "C" void kernel_launch(void* const* d_in, const int* in_sizes, int n_in,
                              void* d_out, int out_size, void* d_ws, size_t ws_size,
                              hipStream_t stream) {
    const int*   sent   = (const int*)d_in[0];
    const float* embed  = (const float*)d_in[1];
    const float* w_ih_f = (const float*)d_in[2];
    const float* w_hh_f = (const float*)d_in[3];
    const float* b_ih_f = (const float*)d_in[4];
    const float* b_hh_f = (const float*)d_in[5];
    const float* w_ih_b = (const float*)d_in[6];
    const float* w_hh_b = (const float*)d_in[7];
    const float* b_ih_b = (const float*)d_in[8];
    const float* b_hh_b = (const float*)d_in[9];
    const float* w_out  = (const float*)d_in[10];
    const float* b_out  = (const float*)d_in[11];
    const float* trans  = (const float*)d_in[12];
    float* out = (float*)d_out;

    unsigned short* G_f = (unsigned short*)d_ws;
    unsigned short* G_b = G_f + (size_t)Tn * Bn * G4;
    unsigned short* h_f = G_b + (size_t)Tn * Bn * G4;
    unsigned short* h_b = h_f + (size_t)Tn * Bn * 128;
    float* feats = (float*)(h_b + (size_t)Tn * Bn * 128);

    k_inproj<<<dim3(512, 4, 2), 256, 0, stream>>>(sent, embed,
        w_ih_f, b_ih_f, b_hh_f, w_ih_b, b_ih_b, b_hh_b, G_f, G_b);
    k_lstm<<<dim3(64, 2), 512, 0, stream>>>(w_hh_f, w_hh_b, G_f, G_b, h_f, h_b);
    k_feats<<<256, 256, 0, stream>>>(h_f, h_b, w_out, b_out, feats);
    k_viterbi<<<64, 64, 0, stream>>>(feats, trans, out);
}